// Round 15
// baseline (87.952 us; speedup 1.0000x reference)
//
#include <hip/hip_runtime.h>

// B=16,S=38 -> ROWS=608; D=1792; H=4, DK=448; NP=128; INF=768
typedef __attribute__((ext_vector_type(8))) short short8v;   // 8 bf16 (4 VGPR)
typedef __attribute__((ext_vector_type(4))) float f32x4;     // MFMA acc

#define APL 5120              // A plane stride (halfwords): 128*40
#define BPL 5184              // B plane stride: 128*40 + 8*8 (group pad)
#define BBASE 15360           // B region start (halfwords): 3*APL

struct SP {
    const float *p0, *p1, *p2, *p3, *p4, *p5, *p6, *p7;
    float *q0, *q1, *q2;
};

__device__ __forceinline__ float wave_sum(float v) {
    #pragma unroll
    for (int off = 32; off; off >>= 1) v += __shfl_down(v, off);
    return v;
}

// out[m*2+c] = A[m,:] @ W[:,c]  (W row-major [K][2]); K % 256 == 0
__device__ __forceinline__ void colvec2_unit(
    const float* __restrict__ A, int lda, const float* __restrict__ W,
    float* __restrict__ out, int K, int m, int lane)
{
    const float4* a = (const float4*)(A + (long)m * lda);
    float a0 = 0.f, a1 = 0.f;
    for (int i = 0; i < K / 256; ++i) {
        const int d4 = lane + 64 * i;
        float4 xv = a[d4];
        const float4* w = (const float4*)(W + (long)d4 * 8);
        float4 w0 = w[0], w1 = w[1];
        a0 += xv.x*w0.x + xv.y*w0.z + xv.z*w1.x + xv.w*w1.z;
        a1 += xv.x*w0.y + xv.y*w0.w + xv.z*w1.y + xv.w*w1.w;
    }
    a0 = wave_sum(a0); a1 = wave_sum(a1);
    if (lane == 0) { out[m * 2 + 0] = a0; out[m * 2 + 1] = a1; }
}

__device__ __forceinline__ void sbias_unit(
    const float* __restrict__ bq, const float* __restrict__ Kp,
    float* __restrict__ sb, int unit, int lane)
{
    const int h = unit >> 7, p = unit & 127;
    const float* kr = Kp + (long)p * 1792 + h * 448;
    const float* bh = bq + h * 448;
    float s = 0.f;
    #pragma unroll
    for (int i = 0; i < 7; ++i) s = fmaf(bh[lane + 64 * i], kr[lane + 64 * i], s);
    s = wave_sum(s);
    if (lane == 0) sb[unit] = s;
}

__device__ __forceinline__ void wvwoq_unit(
    const float* __restrict__ Wv, const float* __restrict__ WoQ,
    float* __restrict__ out, int d, int h, int lane)
{
    const float* wr = Wv + (long)d * 1792 + h * 448;
    const float* wq = WoQ + h * 448 * 2;
    float s0 = 0.f, s1 = 0.f;
    #pragma unroll
    for (int i = 0; i < 7; ++i) {
        const int j = lane + 64 * i;
        const float v = wr[j];
        s0 = fmaf(v, wq[j * 2 + 0], s0);
        s1 = fmaf(v, wq[j * 2 + 1], s1);
    }
    s0 = wave_sum(s0); s1 = wave_sum(s1);
    if (lane == 0) {
        out[((long)h * 1792 + d) * 2 + 0] = s0;
        out[((long)h * 1792 + d) * 2 + 1] = s1;
    }
}

__device__ __forceinline__ void bias_unit(
    const float* __restrict__ bv, const float* __restrict__ WoQ,
    const float* __restrict__ bfc, const float* __restrict__ Wqa,
    const float* __restrict__ bo, const float* __restrict__ WfbQ,
    const float* __restrict__ bqa,
    float* __restrict__ cv, float* __restrict__ const2, int unit, int lane)
{
    float s0 = 0.f, s1 = 0.f;
    if (unit < 4) {
        const int h = unit;
        #pragma unroll
        for (int i = 0; i < 7; ++i) {
            const int j = h * 448 + lane + 64 * i;
            const float v = bv[j];
            s0 = fmaf(v, WoQ[j * 2 + 0], s0);
            s1 = fmaf(v, WoQ[j * 2 + 1], s1);
        }
    } else {
        for (int k = lane; k < 1792; k += 64) {
            if (k < 768) {
                s0 = fmaf(bfc[k], Wqa[k * 2 + 0], s0);
                s1 = fmaf(bfc[k], Wqa[k * 2 + 1], s1);
            }
            s0 = fmaf(bo[k], WfbQ[k * 2 + 0], s0);
            s1 = fmaf(bo[k], WfbQ[k * 2 + 1], s1);
        }
    }
    s0 = wave_sum(s0); s1 = wave_sum(s1);
    if (lane == 0) {
        if (unit < 4) { cv[unit * 2 + 0] = s0; cv[unit * 2 + 1] = s1; }
        else          { const2[0] = s0 + bqa[0]; const2[1] = s1 + bqa[1]; }
    }
}

// fp32 -> 3 bf16 limbs (truncation; residue <= 2^-24 |f|)
__device__ __forceinline__ void split3(float f, unsigned& h, unsigned& m, unsigned& l) {
    unsigned u = __float_as_uint(f);
    h = u >> 16;
    float r1 = f - __uint_as_float(u & 0xFFFF0000u);
    unsigned u1 = __float_as_uint(r1);
    m = u1 >> 16;
    float r2 = r1 - __uint_as_float(u1 & 0xFFFF0000u);
    l = __float_as_uint(r2) >> 16;
}

__device__ __forceinline__ int BROWF(int n) { return n * 40 + (n >> 4) * 8; }

// bf16x3 MFMA GEMM: C = A[M,K] @ op(B), fp32-accurate (6 limb products).
// 256 threads = 4 waves (2x2 of 64x64), 128x128 tile, K-step 32, single-buffer LDS.
// Writes split-K partial slabs [kb*nbb+bb][M][N] at C. z >= mainZ: side tasks.
template<bool TRANSB, int SIDE>
__global__ __launch_bounds__(256) void mgemm(
    const float* __restrict__ A, int lda,
    const float* __restrict__ B, int ldb,
    float* __restrict__ C,
    int M, int N, int K,
    int nsplit, int nbb, int mainZ,
    long sAb, long sBb, SP sp)
{
    const int tid = threadIdx.x;
    if ((int)blockIdx.z >= mainZ) {
        const int bid = ((int)blockIdx.z - mainZ) * (gridDim.x * gridDim.y)
                      + blockIdx.y * gridDim.x + blockIdx.x;
        const int lane = tid & 63;
        const int u = bid * 4 + (tid >> 6);
        if constexpr (SIDE == 1) {
            if (u < 3584) colvec2_unit(sp.p0, 768, sp.p1, sp.q0, 768, u, lane);
        } else if constexpr (SIDE == 2) {
            if (u < 1792)       colvec2_unit(sp.p0, 1792, sp.p1, sp.q0, 1792, u, lane);
            else if (u < 2304)  sbias_unit(sp.p2, sp.p3, sp.q1, u - 1792, lane);
        } else if constexpr (SIDE == 3) {
            if (u < 7168)       wvwoq_unit(sp.p0, sp.p1, sp.q0, u % 1792, u / 1792, lane);
            else if (u < 7173)  bias_unit(sp.p2, sp.p1, sp.p3, sp.p4, sp.p5, sp.p6, sp.p7,
                                          sp.q1, sp.q2, u - 7168, lane);
        }
        return;
    }

    __shared__ unsigned short sh[30912];   // A: 3*5120 ; B: 3*5184  (61824 B)

    const int kb = blockIdx.z % nsplit;
    const int bb = blockIdx.z / nsplit;
    A += sAb * bb;
    B += sBb * bb;
    const int Kc = K / nsplit;
    const int kbeg = kb * Kc;
    const int nsteps = Kc / 32;

    const int lane = tid & 63, wave = tid >> 6;
    const int g = lane >> 4, c = lane & 15;
    const int wm = (wave >> 1) * 64, wn = (wave & 1) * 64;
    const int rowBase = blockIdx.y * 128;
    const int colBase = blockIdx.x * 128;

    // staging maps
    const int s_arow = tid >> 1, s_ak = (tid & 1) * 16;      // A: row, k-offset
    const int s_bk = tid >> 3,  s_bn = (tid & 7) * 16;       // B (!TRANSB): k-row, n-base
    const int s_tn = tid >> 1,  s_tk = (tid & 1) * 16;       // B (TRANSB): n-row, k-offset

    const bool aok = (rowBase + s_arow) < M;
    const float* Arow = A + (long)(rowBase + s_arow) * lda;

    float4 ra[4], rb[4];
    auto loadRaw = [&](int ks) {
        const int k0 = kbeg + ks * 32;
        #pragma unroll
        for (int i = 0; i < 4; ++i)
            ra[i] = aok ? *(const float4*)&Arow[k0 + s_ak + i * 4]
                        : make_float4(0.f, 0.f, 0.f, 0.f);
        if (!TRANSB) {
            const float* bp = B + (long)(k0 + s_bk) * ldb + colBase + s_bn;
            #pragma unroll
            for (int i = 0; i < 4; ++i) rb[i] = *(const float4*)&bp[i * 4];
        } else {
            const float* bp = B + (long)(colBase + s_tn) * ldb + k0 + s_tk;
            #pragma unroll
            for (int i = 0; i < 4; ++i) rb[i] = *(const float4*)&bp[i * 4];
        }
    };

    auto stageWrite = [&]() {
        // ---- A: pack pairs along k, 2 uint4 per plane
        {
            const float* f = (const float*)ra;
            unsigned ph[8], pm[8], pl[8];
            #pragma unroll
            for (int j = 0; j < 8; ++j) {
                unsigned h0, m0, l0, h1, m1, l1;
                split3(f[2*j], h0, m0, l0);
                split3(f[2*j+1], h1, m1, l1);
                ph[j] = h0 | (h1 << 16);
                pm[j] = m0 | (m1 << 16);
                pl[j] = l0 | (l1 << 16);
            }
            const int base = s_arow * 40 + s_ak;
            unsigned short* ap = sh;
            *(uint4*)&ap[0*APL + base]     = make_uint4(ph[0],ph[1],ph[2],ph[3]);
            *(uint4*)&ap[0*APL + base + 8] = make_uint4(ph[4],ph[5],ph[6],ph[7]);
            *(uint4*)&ap[1*APL + base]     = make_uint4(pm[0],pm[1],pm[2],pm[3]);
            *(uint4*)&ap[1*APL + base + 8] = make_uint4(pm[4],pm[5],pm[6],pm[7]);
            *(uint4*)&ap[2*APL + base]     = make_uint4(pl[0],pl[1],pl[2],pl[3]);
            *(uint4*)&ap[2*APL + base + 8] = make_uint4(pl[4],pl[5],pl[6],pl[7]);
        }
        // ---- B
        unsigned short* bp = sh + BBASE;
        if (!TRANSB) {
            // 16 n-values at one k: scalar b16 writes (2-way conflict via group pad)
            const float* f = (const float*)rb;
            #pragma unroll
            for (int j = 0; j < 16; ++j) {
                unsigned h, m, l;
                split3(f[j], h, m, l);
                const int ad = BROWF(s_bn + j) + s_bk;
                bp[0*BPL + ad] = (unsigned short)h;
                bp[1*BPL + ad] = (unsigned short)m;
                bp[2*BPL + ad] = (unsigned short)l;
            }
        } else {
            // one n-row, 16 k contiguous: pack pairs, 2 uint4 per plane
            const float* f = (const float*)rb;
            unsigned ph[8], pm[8], pl[8];
            #pragma unroll
            for (int j = 0; j < 8; ++j) {
                unsigned h0, m0, l0, h1, m1, l1;
                split3(f[2*j], h0, m0, l0);
                split3(f[2*j+1], h1, m1, l1);
                ph[j] = h0 | (h1 << 16);
                pm[j] = m0 | (m1 << 16);
                pl[j] = l0 | (l1 << 16);
            }
            const int base = BROWF(s_tn) + s_tk;
            *(uint4*)&bp[0*BPL + base]     = make_uint4(ph[0],ph[1],ph[2],ph[3]);
            *(uint4*)&bp[0*BPL + base + 8] = make_uint4(ph[4],ph[5],ph[6],ph[7]);
            *(uint4*)&bp[1*BPL + base]     = make_uint4(pm[0],pm[1],pm[2],pm[3]);
            *(uint4*)&bp[1*BPL + base + 8] = make_uint4(pm[4],pm[5],pm[6],pm[7]);
            *(uint4*)&bp[2*BPL + base]     = make_uint4(pl[0],pl[1],pl[2],pl[3]);
            *(uint4*)&bp[2*BPL + base + 8] = make_uint4(pl[4],pl[5],pl[6],pl[7]);
        }
    };

    f32x4 acc[4][4];
    #pragma unroll
    for (int i = 0; i < 4; ++i)
        #pragma unroll
        for (int j = 0; j < 4; ++j)
            acc[i][j] = (f32x4){0.f, 0.f, 0.f, 0.f};

    loadRaw(0);
    for (int s = 0; s < nsteps; ++s) {
        __syncthreads();           // readers of previous step done
        stageWrite();
        if (s + 1 < nsteps) loadRaw(s + 1);
        __syncthreads();           // LDS visible

        const unsigned short* ap = sh;
        const unsigned short* bp = sh + BBASE;
        short8v bfr[3][4];
        #pragma unroll
        for (int ni = 0; ni < 4; ++ni) {
            const int hwb = (wn + 16*ni + c) * 40 + ((wn + 16*ni) >> 4) * 8 + 8 * g;
            bfr[0][ni] = *(const short8v*)&bp[0*BPL + hwb];
            bfr[1][ni] = *(const short8v*)&bp[1*BPL + hwb];
            bfr[2][ni] = *(const short8v*)&bp[2*BPL + hwb];
        }
        #pragma unroll
        for (int mi = 0; mi < 4; ++mi) {
            const int hwa = (wm + 16*mi + c) * 40 + 8 * g;
            short8v ah = *(const short8v*)&ap[0*APL + hwa];
            short8v am = *(const short8v*)&ap[1*APL + hwa];
            short8v al = *(const short8v*)&ap[2*APL + hwa];
            #pragma unroll
            for (int ni = 0; ni < 4; ++ni) {
                f32x4 t = acc[mi][ni];
                t = __builtin_amdgcn_mfma_f32_16x16x32_bf16(ah, bfr[0][ni], t, 0, 0, 0);
                t = __builtin_amdgcn_mfma_f32_16x16x32_bf16(ah, bfr[1][ni], t, 0, 0, 0);
                t = __builtin_amdgcn_mfma_f32_16x16x32_bf16(am, bfr[0][ni], t, 0, 0, 0);
                t = __builtin_amdgcn_mfma_f32_16x16x32_bf16(ah, bfr[2][ni], t, 0, 0, 0);
                t = __builtin_amdgcn_mfma_f32_16x16x32_bf16(am, bfr[1][ni], t, 0, 0, 0);
                t = __builtin_amdgcn_mfma_f32_16x16x32_bf16(al, bfr[0][ni], t, 0, 0, 0);
                acc[mi][ni] = t;
            }
        }
    }

    float* Cw = C + ((long)kb * nbb + bb) * (long)M * N;
    #pragma unroll
    for (int mi = 0; mi < 4; ++mi)
        #pragma unroll
        for (int ni = 0; ni < 4; ++ni) {
            const int col = colBase + wn + 16*ni + c;
            #pragma unroll
            for (int r = 0; r < 4; ++r) {
                const int row = rowBase + wm + 16*mi + 4*g + r;
                if (row < M) Cw[(long)row * N + col] = acc[mi][ni][r];
            }
        }
}

// out[i] = sum_z part[z*sz+i] (+ bias[i%N])
__global__ __launch_bounds__(256) void reduce_add(
    const float* __restrict__ part, float* __restrict__ out,
    const float* __restrict__ bias, int N, long sz, int nsplit)
{
    long i = (long)blockIdx.x * 256 + threadIdx.x;
    const long stride = (long)gridDim.x * 256;
    for (; i < sz; i += stride) {
        float s = 0.f;
        for (int z = 0; z < nsplit; ++z) s += part[z * sz + i];
        if (bias) s += bias[i % N];
        out[i] = s;
    }
}

// One wave per row: per-head argmax over 8 K-split partials (+sbias), then
// logits[row][c] = X[row]@Wbig[:,c] + sum_h proto[i_h]@WvWoQ_h[:,c] + cv + const2
__global__ __launch_bounds__(256) void argmax_final_k(
    const float* __restrict__ Sp,      // [8][4][608][128]
    const float* __restrict__ sbias,   // [4][128]
    const float* __restrict__ X, const float* __restrict__ Wbig,
    const float* __restrict__ WvWoQ,   // [4][1792][2]
    const float* __restrict__ proto,
    const float* __restrict__ cv, const float* __restrict__ const2,
    float* __restrict__ out)
{
    const int lane = threadIdx.x & 63;
    const int row = blockIdx.x * 4 + (threadIdx.x >> 6);
    if (row >= 608) return;

    int sel[4];
    #pragma unroll
    for (int h = 0; h < 4; ++h) {
        float s0 = sbias[h * 128 + lane];
        float s1 = sbias[h * 128 + lane + 64];
        #pragma unroll
        for (int z = 0; z < 8; ++z) {
            const long base = ((long)(z * 4 + h) * 608 + row) * 128;
            s0 += Sp[base + lane];
            s1 += Sp[base + lane + 64];
        }
        float best = s0; int bi = lane;
        if (s1 > best) { best = s1; bi = lane + 64; }
        #pragma unroll
        for (int off = 32; off; off >>= 1) {
            float ov = __shfl_down(best, off);
            int   oi = __shfl_down(bi, off);
            if (ov > best || (ov == best && oi < bi)) { best = ov; bi = oi; }
        }
        sel[h] = __shfl(bi, 0);
    }

    float a0 = 0.f, a1 = 0.f;
    auto dot2 = [&](const float* a, const float* w) {
        const float4* av = (const float4*)a;
        #pragma unroll
        for (int i = 0; i < 7; ++i) {
            const int d4 = lane + 64 * i;
            float4 xv = av[d4];
            const float4* wp = (const float4*)(w + (long)d4 * 8);
            float4 w0 = wp[0], w1 = wp[1];
            a0 += xv.x*w0.x + xv.y*w0.z + xv.z*w1.x + xv.w*w1.z;
            a1 += xv.x*w0.y + xv.y*w0.w + xv.z*w1.y + xv.w*w1.w;
        }
    };
    dot2(X + (long)row * 1792, Wbig);
    #pragma unroll
    for (int h = 0; h < 4; ++h)
        dot2(proto + (long)sel[h] * 1792, WvWoQ + (long)h * 3584);

    a0 = wave_sum(a0); a1 = wave_sum(a1);
    if (lane == 0) {
        out[row * 2 + 0] = a0 + const2[0] + cv[0] + cv[2] + cv[4] + cv[6];
        out[row * 2 + 1] = a1 + const2[1] + cv[1] + cv[3] + cv[5] + cv[7];
    }
}

extern "C" void kernel_launch(void* const* d_in, const int* in_sizes, int n_in,
                              void* d_out, int out_size, void* d_ws, size_t ws_size,
                              hipStream_t stream)
{
    const float* X     = (const float*)d_in[0];   // [608,1792]
    const float* proto = (const float*)d_in[1];   // [128,1792]
    const float* Wq  = (const float*)d_in[3];
    const float* bq  = (const float*)d_in[4];
    const float* Wk  = (const float*)d_in[5];
    const float* bk  = (const float*)d_in[6];
    const float* Wv  = (const float*)d_in[7];
    const float* bv  = (const float*)d_in[8];
    const float* Wo  = (const float*)d_in[9];
    const float* bo  = (const float*)d_in[10];
    const float* Wfc = (const float*)d_in[11];    // [3584,768]
    const float* bfc = (const float*)d_in[12];
    const float* Wqa = (const float*)d_in[13];    // [768,2]
    const float* bqa = (const float*)d_in[14];
    float* out = (float*)d_out;

    // workspace (floats)
    float* ws = (float*)d_ws;
    float* P      = ws;                 // up to 3,211,264 partials (reused per phase)
    float* Kp     = P + 3211264;        // 229,376  [128][1792]
    float* W2b    = Kp + 229376;        // 917,504  [4][1792][128]
    float* sbias  = W2b + 917504;       // 512
    float* WbigB  = sbias + 512;        // 7,168    [3584][2] (top=Wbig, bottom=WfbQ)
    float* WoQ    = WbigB + 7168;       // 3,584    [1792][2]
    float* WvWoQ  = WoQ + 3584;         // 14,336   [4][1792][2]
    float* cv     = WvWoQ + 14336;      // 8
    float* const2 = cv + 8;             // 2 (+6 pad)
    float* WfbQ   = WbigB + 3584;

    dim3 blk(256);

    // L1: Kp partials = proto @ Wk  [split 14, Kc=128 -> 196 gemm blocks]
    //     side: WbigB = Wfc @ Wqa  (3584 units -> 896 bids over gx*gy=14 -> 64 z)
    {
        SP sp{}; sp.p0 = Wfc; sp.p1 = Wqa; sp.q0 = WbigB;
        mgemm<false, 1><<<dim3(14, 1, 14 + 64), blk, 0, stream>>>(
            proto, 1792, Wk, 1792, P, 128, 1792, 1792, 14, 1, 14, 0, 0, sp);
    }
    // L2: Kp = sum 14 partials + bk
    reduce_add<<<dim3(896), blk, 0, stream>>>(P, Kp, bk, 1792, 229376L, 14);

    // L3: W2b = Wq_h @ Kp_h^T  [batch 4, UNSPLIT, nsteps=14 -> 56 gemm blocks]
    //     writes W2b directly (kb=0, slab index = bb) -> L4 reduce deleted
    //     side: WoQ = Wo@WfbQ (1792) + sbias (512) -> 576 bids over 14 -> 42 z
    {
        SP sp{}; sp.p0 = Wo; sp.p1 = WfbQ; sp.q0 = WoQ; sp.p2 = bq; sp.p3 = Kp; sp.q1 = sbias;
        mgemm<true, 2><<<dim3(1, 14, 4 + 42), blk, 0, stream>>>(
            Wq, 1792, Kp, 1792, W2b, 1792, 128, 448, 1, 4, 4, 448, 448, sp);
    }
    // L4: Sc partials = X @ W2b[h]  [batch 4, split 8, Kc=224 -> 160 blocks]
    //     side: WvWoQ (7168) + bias (5) -> 1794 bids over gx*gy=5 -> 359 z
    {
        SP sp{}; sp.p0 = Wv; sp.p1 = WoQ; sp.q0 = WvWoQ;
        sp.p2 = bv; sp.p3 = bfc; sp.p4 = Wqa; sp.p5 = bo; sp.p6 = WfbQ; sp.p7 = bqa;
        sp.q1 = cv; sp.q2 = const2;
        mgemm<false, 3><<<dim3(1, 5, 32 + 359), blk, 0, stream>>>(
            X, 1792, W2b, 128, P, 608, 128, 1792, 8, 4, 32, 0, 229376L, sp);
    }
    // L5: per-(row,head) argmax + logits
    argmax_final_k<<<dim3(152), blk, 0, stream>>>(
        P, sbias, X, WbigB, WvWoQ, proto, cv, const2, out);
}

// Round 16
// 80.532 us; speedup vs baseline: 1.0921x; 1.0921x over previous
//
#include <hip/hip_runtime.h>

// B=16,S=38 -> ROWS=608; D=1792; H=4, DK=448; NP=128; INF=768
typedef __attribute__((ext_vector_type(8))) short short8v;   // 8 bf16 (4 VGPR)
typedef __attribute__((ext_vector_type(4))) float f32x4;     // MFMA acc

#define APL 5120              // A plane stride (halfwords): 128*40
#define BPL 5184              // B plane stride: 128*40 + 8*8 (group pad)
#define BBASE 15360           // B region start (halfwords): 3*APL

struct SP {
    const float *p0, *p1, *p2, *p3, *p4, *p5, *p6, *p7;
    float *q0, *q1, *q2;
};

__device__ __forceinline__ float wave_sum(float v) {
    #pragma unroll
    for (int off = 32; off; off >>= 1) v += __shfl_down(v, off);
    return v;
}

// out[m*2+c] = A[m,:] @ W[:,c]  (W row-major [K][2]); K % 256 == 0
__device__ __forceinline__ void colvec2_unit(
    const float* __restrict__ A, int lda, const float* __restrict__ W,
    float* __restrict__ out, int K, int m, int lane)
{
    const float4* a = (const float4*)(A + (long)m * lda);
    float a0 = 0.f, a1 = 0.f;
    for (int i = 0; i < K / 256; ++i) {
        const int d4 = lane + 64 * i;
        float4 xv = a[d4];
        const float4* w = (const float4*)(W + (long)d4 * 8);
        float4 w0 = w[0], w1 = w[1];
        a0 += xv.x*w0.x + xv.y*w0.z + xv.z*w1.x + xv.w*w1.z;
        a1 += xv.x*w0.y + xv.y*w0.w + xv.z*w1.y + xv.w*w1.w;
    }
    a0 = wave_sum(a0); a1 = wave_sum(a1);
    if (lane == 0) { out[m * 2 + 0] = a0; out[m * 2 + 1] = a1; }
}

__device__ __forceinline__ void sbias_unit(
    const float* __restrict__ bq, const float* __restrict__ Kp,
    float* __restrict__ sb, int unit, int lane)
{
    const int h = unit >> 7, p = unit & 127;
    const float* kr = Kp + (long)p * 1792 + h * 448;
    const float* bh = bq + h * 448;
    float s = 0.f;
    #pragma unroll
    for (int i = 0; i < 7; ++i) s = fmaf(bh[lane + 64 * i], kr[lane + 64 * i], s);
    s = wave_sum(s);
    if (lane == 0) sb[unit] = s;
}

__device__ __forceinline__ void wvwoq_unit(
    const float* __restrict__ Wv, const float* __restrict__ WoQ,
    float* __restrict__ out, int d, int h, int lane)
{
    const float* wr = Wv + (long)d * 1792 + h * 448;
    const float* wq = WoQ + h * 448 * 2;
    float s0 = 0.f, s1 = 0.f;
    #pragma unroll
    for (int i = 0; i < 7; ++i) {
        const int j = lane + 64 * i;
        const float v = wr[j];
        s0 = fmaf(v, wq[j * 2 + 0], s0);
        s1 = fmaf(v, wq[j * 2 + 1], s1);
    }
    s0 = wave_sum(s0); s1 = wave_sum(s1);
    if (lane == 0) {
        out[((long)h * 1792 + d) * 2 + 0] = s0;
        out[((long)h * 1792 + d) * 2 + 1] = s1;
    }
}

__device__ __forceinline__ void bias_unit(
    const float* __restrict__ bv, const float* __restrict__ WoQ,
    const float* __restrict__ bfc, const float* __restrict__ Wqa,
    const float* __restrict__ bo, const float* __restrict__ WfbQ,
    const float* __restrict__ bqa,
    float* __restrict__ cv, float* __restrict__ const2, int unit, int lane)
{
    float s0 = 0.f, s1 = 0.f;
    if (unit < 4) {
        const int h = unit;
        #pragma unroll
        for (int i = 0; i < 7; ++i) {
            const int j = h * 448 + lane + 64 * i;
            const float v = bv[j];
            s0 = fmaf(v, WoQ[j * 2 + 0], s0);
            s1 = fmaf(v, WoQ[j * 2 + 1], s1);
        }
    } else {
        for (int k = lane; k < 1792; k += 64) {
            if (k < 768) {
                s0 = fmaf(bfc[k], Wqa[k * 2 + 0], s0);
                s1 = fmaf(bfc[k], Wqa[k * 2 + 1], s1);
            }
            s0 = fmaf(bo[k], WfbQ[k * 2 + 0], s0);
            s1 = fmaf(bo[k], WfbQ[k * 2 + 1], s1);
        }
    }
    s0 = wave_sum(s0); s1 = wave_sum(s1);
    if (lane == 0) {
        if (unit < 4) { cv[unit * 2 + 0] = s0; cv[unit * 2 + 1] = s1; }
        else          { const2[0] = s0 + bqa[0]; const2[1] = s1 + bqa[1]; }
    }
}

// fp32 -> 3 bf16 limbs (truncation; residue <= 2^-24 |f|)
__device__ __forceinline__ void split3(float f, unsigned& h, unsigned& m, unsigned& l) {
    unsigned u = __float_as_uint(f);
    h = u >> 16;
    float r1 = f - __uint_as_float(u & 0xFFFF0000u);
    unsigned u1 = __float_as_uint(r1);
    m = u1 >> 16;
    float r2 = r1 - __uint_as_float(u1 & 0xFFFF0000u);
    l = __float_as_uint(r2) >> 16;
}

__device__ __forceinline__ int BROWF(int n) { return n * 40 + (n >> 4) * 8; }

// bf16x3 MFMA GEMM: C = A[M,K] @ op(B), fp32-accurate (6 limb products).
// 256 threads = 4 waves (2x2 of 64x64), 128x128 tile, K-step 32, single-buffer LDS.
// Writes split-K partial slabs [kb*nbb+bb][M][N] at C. z >= mainZ: side tasks.
template<bool TRANSB, int SIDE>
__global__ __launch_bounds__(256) void mgemm(
    const float* __restrict__ A, int lda,
    const float* __restrict__ B, int ldb,
    float* __restrict__ C,
    int M, int N, int K,
    int nsplit, int nbb, int mainZ,
    long sAb, long sBb, SP sp)
{
    const int tid = threadIdx.x;
    if ((int)blockIdx.z >= mainZ) {
        const int bid = ((int)blockIdx.z - mainZ) * (gridDim.x * gridDim.y)
                      + blockIdx.y * gridDim.x + blockIdx.x;
        const int lane = tid & 63;
        const int u = bid * 4 + (tid >> 6);
        if constexpr (SIDE == 1) {
            if (u < 3584) colvec2_unit(sp.p0, 768, sp.p1, sp.q0, 768, u, lane);
        } else if constexpr (SIDE == 2) {
            if (u < 1792)       colvec2_unit(sp.p0, 1792, sp.p1, sp.q0, 1792, u, lane);
            else if (u < 2304)  sbias_unit(sp.p2, sp.p3, sp.q1, u - 1792, lane);
        } else if constexpr (SIDE == 3) {
            if (u < 7168)       wvwoq_unit(sp.p0, sp.p1, sp.q0, u % 1792, u / 1792, lane);
            else if (u < 7173)  bias_unit(sp.p2, sp.p1, sp.p3, sp.p4, sp.p5, sp.p6, sp.p7,
                                          sp.q1, sp.q2, u - 7168, lane);
        }
        return;
    }

    __shared__ unsigned short sh[30912];   // A: 3*5120 ; B: 3*5184  (61824 B)

    const int kb = blockIdx.z % nsplit;
    const int bb = blockIdx.z / nsplit;
    A += sAb * bb;
    B += sBb * bb;
    const int Kc = K / nsplit;
    const int kbeg = kb * Kc;
    const int nsteps = Kc / 32;

    const int lane = tid & 63, wave = tid >> 6;
    const int g = lane >> 4, c = lane & 15;
    const int wm = (wave >> 1) * 64, wn = (wave & 1) * 64;
    const int rowBase = blockIdx.y * 128;
    const int colBase = blockIdx.x * 128;

    // staging maps
    const int s_arow = tid >> 1, s_ak = (tid & 1) * 16;      // A: row, k-offset
    const int s_bk = tid >> 3,  s_bn = (tid & 7) * 16;       // B (!TRANSB): k-row, n-base
    const int s_tn = tid >> 1,  s_tk = (tid & 1) * 16;       // B (TRANSB): n-row, k-offset

    const bool aok = (rowBase + s_arow) < M;
    const float* Arow = A + (long)(rowBase + s_arow) * lda;

    float4 ra[4], rb[4];
    auto loadRaw = [&](int ks) {
        const int k0 = kbeg + ks * 32;
        #pragma unroll
        for (int i = 0; i < 4; ++i)
            ra[i] = aok ? *(const float4*)&Arow[k0 + s_ak + i * 4]
                        : make_float4(0.f, 0.f, 0.f, 0.f);
        if (!TRANSB) {
            const float* bp = B + (long)(k0 + s_bk) * ldb + colBase + s_bn;
            #pragma unroll
            for (int i = 0; i < 4; ++i) rb[i] = *(const float4*)&bp[i * 4];
        } else {
            const float* bp = B + (long)(colBase + s_tn) * ldb + k0 + s_tk;
            #pragma unroll
            for (int i = 0; i < 4; ++i) rb[i] = *(const float4*)&bp[i * 4];
        }
    };

    auto stageWrite = [&]() {
        // ---- A: pack pairs along k, 2 uint4 per plane
        {
            const float* f = (const float*)ra;
            unsigned ph[8], pm[8], pl[8];
            #pragma unroll
            for (int j = 0; j < 8; ++j) {
                unsigned h0, m0, l0, h1, m1, l1;
                split3(f[2*j], h0, m0, l0);
                split3(f[2*j+1], h1, m1, l1);
                ph[j] = h0 | (h1 << 16);
                pm[j] = m0 | (m1 << 16);
                pl[j] = l0 | (l1 << 16);
            }
            const int base = s_arow * 40 + s_ak;
            unsigned short* ap = sh;
            *(uint4*)&ap[0*APL + base]     = make_uint4(ph[0],ph[1],ph[2],ph[3]);
            *(uint4*)&ap[0*APL + base + 8] = make_uint4(ph[4],ph[5],ph[6],ph[7]);
            *(uint4*)&ap[1*APL + base]     = make_uint4(pm[0],pm[1],pm[2],pm[3]);
            *(uint4*)&ap[1*APL + base + 8] = make_uint4(pm[4],pm[5],pm[6],pm[7]);
            *(uint4*)&ap[2*APL + base]     = make_uint4(pl[0],pl[1],pl[2],pl[3]);
            *(uint4*)&ap[2*APL + base + 8] = make_uint4(pl[4],pl[5],pl[6],pl[7]);
        }
        // ---- B
        unsigned short* bp = sh + BBASE;
        if (!TRANSB) {
            // 16 n-values at one k: scalar b16 writes (2-way conflict via group pad)
            const float* f = (const float*)rb;
            #pragma unroll
            for (int j = 0; j < 16; ++j) {
                unsigned h, m, l;
                split3(f[j], h, m, l);
                const int ad = BROWF(s_bn + j) + s_bk;
                bp[0*BPL + ad] = (unsigned short)h;
                bp[1*BPL + ad] = (unsigned short)m;
                bp[2*BPL + ad] = (unsigned short)l;
            }
        } else {
            // one n-row, 16 k contiguous: pack pairs, 2 uint4 per plane
            const float* f = (const float*)rb;
            unsigned ph[8], pm[8], pl[8];
            #pragma unroll
            for (int j = 0; j < 8; ++j) {
                unsigned h0, m0, l0, h1, m1, l1;
                split3(f[2*j], h0, m0, l0);
                split3(f[2*j+1], h1, m1, l1);
                ph[j] = h0 | (h1 << 16);
                pm[j] = m0 | (m1 << 16);
                pl[j] = l0 | (l1 << 16);
            }
            const int base = BROWF(s_tn) + s_tk;
            *(uint4*)&bp[0*BPL + base]     = make_uint4(ph[0],ph[1],ph[2],ph[3]);
            *(uint4*)&bp[0*BPL + base + 8] = make_uint4(ph[4],ph[5],ph[6],ph[7]);
            *(uint4*)&bp[1*BPL + base]     = make_uint4(pm[0],pm[1],pm[2],pm[3]);
            *(uint4*)&bp[1*BPL + base + 8] = make_uint4(pm[4],pm[5],pm[6],pm[7]);
            *(uint4*)&bp[2*BPL + base]     = make_uint4(pl[0],pl[1],pl[2],pl[3]);
            *(uint4*)&bp[2*BPL + base + 8] = make_uint4(pl[4],pl[5],pl[6],pl[7]);
        }
    };

    f32x4 acc[4][4];
    #pragma unroll
    for (int i = 0; i < 4; ++i)
        #pragma unroll
        for (int j = 0; j < 4; ++j)
            acc[i][j] = (f32x4){0.f, 0.f, 0.f, 0.f};

    loadRaw(0);
    for (int s = 0; s < nsteps; ++s) {
        __syncthreads();           // readers of previous step done
        stageWrite();
        if (s + 1 < nsteps) loadRaw(s + 1);
        __syncthreads();           // LDS visible

        const unsigned short* ap = sh;
        const unsigned short* bp = sh + BBASE;
        short8v bfr[3][4];
        #pragma unroll
        for (int ni = 0; ni < 4; ++ni) {
            const int hwb = (wn + 16*ni + c) * 40 + ((wn + 16*ni) >> 4) * 8 + 8 * g;
            bfr[0][ni] = *(const short8v*)&bp[0*BPL + hwb];
            bfr[1][ni] = *(const short8v*)&bp[1*BPL + hwb];
            bfr[2][ni] = *(const short8v*)&bp[2*BPL + hwb];
        }
        #pragma unroll
        for (int mi = 0; mi < 4; ++mi) {
            const int hwa = (wm + 16*mi + c) * 40 + 8 * g;
            short8v ah = *(const short8v*)&ap[0*APL + hwa];
            short8v am = *(const short8v*)&ap[1*APL + hwa];
            short8v al = *(const short8v*)&ap[2*APL + hwa];
            #pragma unroll
            for (int ni = 0; ni < 4; ++ni) {
                f32x4 t = acc[mi][ni];
                t = __builtin_amdgcn_mfma_f32_16x16x32_bf16(ah, bfr[0][ni], t, 0, 0, 0);
                t = __builtin_amdgcn_mfma_f32_16x16x32_bf16(ah, bfr[1][ni], t, 0, 0, 0);
                t = __builtin_amdgcn_mfma_f32_16x16x32_bf16(am, bfr[0][ni], t, 0, 0, 0);
                t = __builtin_amdgcn_mfma_f32_16x16x32_bf16(ah, bfr[2][ni], t, 0, 0, 0);
                t = __builtin_amdgcn_mfma_f32_16x16x32_bf16(am, bfr[1][ni], t, 0, 0, 0);
                t = __builtin_amdgcn_mfma_f32_16x16x32_bf16(al, bfr[0][ni], t, 0, 0, 0);
                acc[mi][ni] = t;
            }
        }
    }

    float* Cw = C + ((long)kb * nbb + bb) * (long)M * N;
    #pragma unroll
    for (int mi = 0; mi < 4; ++mi)
        #pragma unroll
        for (int ni = 0; ni < 4; ++ni) {
            const int col = colBase + wn + 16*ni + c;
            #pragma unroll
            for (int r = 0; r < 4; ++r) {
                const int row = rowBase + wm + 16*mi + 4*g + r;
                if (row < M) Cw[(long)row * N + col] = acc[mi][ni][r];
            }
        }
}

// out[i] = sum_z part[z*sz+i] (+ bias[i%N])
__global__ __launch_bounds__(256) void reduce_add(
    const float* __restrict__ part, float* __restrict__ out,
    const float* __restrict__ bias, int N, long sz, int nsplit)
{
    long i = (long)blockIdx.x * 256 + threadIdx.x;
    const long stride = (long)gridDim.x * 256;
    for (; i < sz; i += stride) {
        float s = 0.f;
        for (int z = 0; z < nsplit; ++z) s += part[z * sz + i];
        if (bias) s += bias[i % N];
        out[i] = s;
    }
}

// One wave per row: per-head argmax over 8 K-split partials (+sbias), then
// logits[row][c] = X[row]@Wbig[:,c] + sum_h proto[i_h]@WvWoQ_h[:,c] + cv + const2
__global__ __launch_bounds__(256) void argmax_final_k(
    const float* __restrict__ Sp,      // [8][4][608][128]
    const float* __restrict__ sbias,   // [4][128]
    const float* __restrict__ X, const float* __restrict__ Wbig,
    const float* __restrict__ WvWoQ,   // [4][1792][2]
    const float* __restrict__ proto,
    const float* __restrict__ cv, const float* __restrict__ const2,
    float* __restrict__ out)
{
    const int lane = threadIdx.x & 63;
    const int row = blockIdx.x * 4 + (threadIdx.x >> 6);
    if (row >= 608) return;

    int sel[4];
    #pragma unroll
    for (int h = 0; h < 4; ++h) {
        float s0 = sbias[h * 128 + lane];
        float s1 = sbias[h * 128 + lane + 64];
        #pragma unroll
        for (int z = 0; z < 8; ++z) {
            const long base = ((long)(z * 4 + h) * 608 + row) * 128;
            s0 += Sp[base + lane];
            s1 += Sp[base + lane + 64];
        }
        float best = s0; int bi = lane;
        if (s1 > best) { best = s1; bi = lane + 64; }
        #pragma unroll
        for (int off = 32; off; off >>= 1) {
            float ov = __shfl_down(best, off);
            int   oi = __shfl_down(bi, off);
            if (ov > best || (ov == best && oi < bi)) { best = ov; bi = oi; }
        }
        sel[h] = __shfl(bi, 0);
    }

    float a0 = 0.f, a1 = 0.f;
    auto dot2 = [&](const float* a, const float* w) {
        const float4* av = (const float4*)a;
        #pragma unroll
        for (int i = 0; i < 7; ++i) {
            const int d4 = lane + 64 * i;
            float4 xv = av[d4];
            const float4* wp = (const float4*)(w + (long)d4 * 8);
            float4 w0 = wp[0], w1 = wp[1];
            a0 += xv.x*w0.x + xv.y*w0.z + xv.z*w1.x + xv.w*w1.z;
            a1 += xv.x*w0.y + xv.y*w0.w + xv.z*w1.y + xv.w*w1.w;
        }
    };
    dot2(X + (long)row * 1792, Wbig);
    #pragma unroll
    for (int h = 0; h < 4; ++h)
        dot2(proto + (long)sel[h] * 1792, WvWoQ + (long)h * 3584);

    a0 = wave_sum(a0); a1 = wave_sum(a1);
    if (lane == 0) {
        out[row * 2 + 0] = a0 + const2[0] + cv[0] + cv[2] + cv[4] + cv[6];
        out[row * 2 + 1] = a1 + const2[1] + cv[1] + cv[3] + cv[5] + cv[7];
    }
}

extern "C" void kernel_launch(void* const* d_in, const int* in_sizes, int n_in,
                              void* d_out, int out_size, void* d_ws, size_t ws_size,
                              hipStream_t stream)
{
    const float* X     = (const float*)d_in[0];   // [608,1792]
    const float* proto = (const float*)d_in[1];   // [128,1792]
    const float* Wq  = (const float*)d_in[3];
    const float* bq  = (const float*)d_in[4];
    const float* Wk  = (const float*)d_in[5];
    const float* bk  = (const float*)d_in[6];
    const float* Wv  = (const float*)d_in[7];
    const float* bv  = (const float*)d_in[8];
    const float* Wo  = (const float*)d_in[9];
    const float* bo  = (const float*)d_in[10];
    const float* Wfc = (const float*)d_in[11];    // [3584,768]
    const float* bfc = (const float*)d_in[12];
    const float* Wqa = (const float*)d_in[13];    // [768,2]
    const float* bqa = (const float*)d_in[14];
    float* out = (float*)d_out;

    // workspace (floats)
    float* ws = (float*)d_ws;
    float* P      = ws;                 // up to 3,211,264 partials (reused per phase)
    float* Kp     = P + 3211264;        // 229,376  [128][1792]
    float* W2b    = Kp + 229376;        // 917,504  [4][1792][128]
    float* sbias  = W2b + 917504;       // 512
    float* WbigB  = sbias + 512;        // 7,168    [3584][2] (top=Wbig, bottom=WfbQ)
    float* WoQ    = WbigB + 7168;       // 3,584    [1792][2]
    float* WvWoQ  = WoQ + 3584;         // 14,336   [4][1792][2]
    float* cv     = WvWoQ + 14336;      // 8
    float* const2 = cv + 8;             // 2 (+6 pad)
    float* WfbQ   = WbigB + 3584;

    dim3 blk(256);

    // L1: Kp partials = proto @ Wk  [split 14, Kc=128 -> 196 gemm blocks]
    //     side: WbigB = Wfc @ Wqa  (3584 units -> 896 bids over gx*gy=14 -> 64 z)
    {
        SP sp{}; sp.p0 = Wfc; sp.p1 = Wqa; sp.q0 = WbigB;
        mgemm<false, 1><<<dim3(14, 1, 14 + 64), blk, 0, stream>>>(
            proto, 1792, Wk, 1792, P, 128, 1792, 1792, 14, 1, 14, 0, 0, sp);
    }
    // L2: Kp = sum 14 partials + bk
    reduce_add<<<dim3(896), blk, 0, stream>>>(P, Kp, bk, 1792, 229376L, 14);

    // L3: W2 partials = Wq_h @ Kp_h^T  [batch 4, split 2, Kc=224 -> 112 blocks]
    //     side: WoQ = Wo@WfbQ (1792) + sbias (512) -> 576 bids over 14 -> 42 z
    {
        SP sp{}; sp.p0 = Wo; sp.p1 = WfbQ; sp.q0 = WoQ; sp.p2 = bq; sp.p3 = Kp; sp.q1 = sbias;
        mgemm<true, 2><<<dim3(1, 14, 8 + 42), blk, 0, stream>>>(
            Wq, 1792, Kp, 1792, P, 1792, 128, 448, 2, 4, 8, 448, 448, sp);
    }
    // L4: W2b = sum 2 partials
    reduce_add<<<dim3(1792), blk, 0, stream>>>(P, W2b, nullptr, 1, 917504L, 2);

    // L5: Sc partials = X @ W2b[h]  [batch 4, split 8, Kc=224 -> 160 blocks]
    //     side: WvWoQ (7168) + bias (5) -> 1794 bids over gx*gy=5 -> 359 z
    {
        SP sp{}; sp.p0 = Wv; sp.p1 = WoQ; sp.q0 = WvWoQ;
        sp.p2 = bv; sp.p3 = bfc; sp.p4 = Wqa; sp.p5 = bo; sp.p6 = WfbQ; sp.p7 = bqa;
        sp.q1 = cv; sp.q2 = const2;
        mgemm<false, 3><<<dim3(1, 5, 32 + 359), blk, 0, stream>>>(
            X, 1792, W2b, 128, P, 608, 128, 1792, 8, 4, 32, 0, 229376L, sp);
    }
    // L6: per-(row,head) argmax + logits
    argmax_final_k<<<dim3(152), blk, 0, stream>>>(
        P, sbias, X, WbigB, WvWoQ, proto, cv, const2, out);
}